// Round 1
// baseline (1037.142 us; speedup 1.0000x reference)
//
#include <hip/hip_runtime.h>
#include <math.h>

#define D      16384
#define S      2048
#define NF     40
#define ROWS   8      // rows of X per block
#define TPB    1024   // threads per block
#define VEC    4      // float4 chunks per row per thread = D/4/TPB

// ---------------------------------------------------------------------------
// Kernel 1: per-flow scalar coefficient
//   coef[k] = ((-1 + softplus(w.u)) - w.u) / (w.w)
// so that u_hat = u + coef * w.
// ---------------------------------------------------------------------------
__global__ __launch_bounds__(256) void coef_kernel(const float* __restrict__ ws,
                                                   const float* __restrict__ us,
                                                   float* __restrict__ coefs) {
    const int k = blockIdx.x;
    const float4* w4 = (const float4*)(ws + (size_t)k * D);
    const float4* u4 = (const float4*)(us + (size_t)k * D);
    float ww = 0.f, wu = 0.f;
    for (int i = threadIdx.x; i < D / 4; i += 256) {
        float4 w = w4[i], u = u4[i];
        ww += w.x * w.x + w.y * w.y + w.z * w.z + w.w * w.w;
        wu += w.x * u.x + w.y * u.y + w.z * u.z + w.w * u.w;
    }
    #pragma unroll
    for (int off = 32; off >= 1; off >>= 1) {
        ww += __shfl_xor(ww, off);
        wu += __shfl_xor(wu, off);
    }
    __shared__ float sww[4], swu[4];
    const int wave = threadIdx.x >> 6;
    if ((threadIdx.x & 63) == 0) { sww[wave] = ww; swu[wave] = wu; }
    __syncthreads();
    if (threadIdx.x == 0) {
        ww = sww[0] + sww[1] + sww[2] + sww[3];
        wu = swu[0] + swu[1] + swu[2] + swu[3];
        // numerically stable softplus
        float sp = (wu > 0.f) ? (wu + log1pf(expf(-wu))) : log1pf(expf(wu));
        float m  = -1.f + sp;
        coefs[k] = (m - wu) / ww;
    }
}

// ---------------------------------------------------------------------------
// Kernel 2: full 40-flow chain with X register-resident.
// Each block owns ROWS full rows of X. Per flow:
//   1. thread-local dot partials (x . w)
//   2. wave shfl_xor reduce (64 lanes)
//   3. cross-wave reduce via LDS (16 wave-partials per row, 2 waves do stage 2)
//   4. act[r] = tanh(dot + b) broadcast via LDS
//   5. in-register rank-1 update x += act[r] * (u + coef*w)
// Double-buffered LDS scratch -> 2 barriers per flow.
// ---------------------------------------------------------------------------
__global__ __launch_bounds__(TPB, 1) void flow_kernel(const float* __restrict__ X,
                                                      const float* __restrict__ ws,
                                                      const float* __restrict__ us,
                                                      const float* __restrict__ bs,
                                                      const float* __restrict__ coefs,
                                                      float* __restrict__ out) {
    const int t = threadIdx.x;
    const int wave = t >> 6;
    const int lane = t & 63;
    const int rowBase = blockIdx.x * ROWS;

    const float4* X4 = (const float4*)X;
    float4* O4 = (float4*)out;

    // Load this block's 8 rows into registers (coalesced float4).
    float4 x[ROWS][VEC];
    #pragma unroll
    for (int r = 0; r < ROWS; ++r) {
        const size_t base = (size_t)(rowBase + r) * (D / 4);
        #pragma unroll
        for (int j = 0; j < VEC; ++j)
            x[r][j] = X4[base + t + j * TPB];
    }

    __shared__ float red[2][16][ROWS];   // [buf][wave][row]
    __shared__ float actS[2][ROWS];      // [buf][row]

    for (int k = 0; k < NF; ++k) {
        const int buf = k & 1;
        const float4* w4 = (const float4*)(ws + (size_t)k * D);
        const float4* u4 = (const float4*)(us + (size_t)k * D);

        float4 wv[VEC], uv[VEC];
        #pragma unroll
        for (int j = 0; j < VEC; ++j) {
            wv[j] = w4[t + j * TPB];
            uv[j] = u4[t + j * TPB];
        }

        // 1. thread-local dot partials
        float part[ROWS];
        #pragma unroll
        for (int r = 0; r < ROWS; ++r) {
            float s = 0.f;
            #pragma unroll
            for (int j = 0; j < VEC; ++j) {
                s += x[r][j].x * wv[j].x + x[r][j].y * wv[j].y +
                     x[r][j].z * wv[j].z + x[r][j].w * wv[j].w;
            }
            part[r] = s;
        }

        // 2. wave-level reduce (all 64 lanes)
        #pragma unroll
        for (int r = 0; r < ROWS; ++r) {
            float s = part[r];
            #pragma unroll
            for (int off = 32; off >= 1; off >>= 1) s += __shfl_xor(s, off);
            part[r] = s;
        }
        if (lane == 0) {
            #pragma unroll
            for (int r = 0; r < ROWS; ++r) red[buf][wave][r] = part[r];
        }
        __syncthreads();

        // 3.+4. cross-wave reduce: 128 threads; thread i -> row i>>4, wavepart i&15
        if (t < 16 * ROWS) {
            const int r = t >> 4, w16 = t & 15;
            float s = red[buf][w16][r];
            s += __shfl_xor(s, 8);
            s += __shfl_xor(s, 4);
            s += __shfl_xor(s, 2);
            s += __shfl_xor(s, 1);
            if (w16 == 0) actS[buf][r] = tanhf(s + bs[k]);
        }
        __syncthreads();

        // 5. rank-1 update in registers
        const float coef = coefs[k];
        float act[ROWS];
        #pragma unroll
        for (int r = 0; r < ROWS; ++r) act[r] = actS[buf][r];

        float4 uh[VEC];
        #pragma unroll
        for (int j = 0; j < VEC; ++j) {
            uh[j].x = uv[j].x + coef * wv[j].x;
            uh[j].y = uv[j].y + coef * wv[j].y;
            uh[j].z = uv[j].z + coef * wv[j].z;
            uh[j].w = uv[j].w + coef * wv[j].w;
        }
        #pragma unroll
        for (int r = 0; r < ROWS; ++r) {
            #pragma unroll
            for (int j = 0; j < VEC; ++j) {
                x[r][j].x += act[r] * uh[j].x;
                x[r][j].y += act[r] * uh[j].y;
                x[r][j].z += act[r] * uh[j].z;
                x[r][j].w += act[r] * uh[j].w;
            }
        }
    }

    // Store final X to d_out (coalesced float4).
    #pragma unroll
    for (int r = 0; r < ROWS; ++r) {
        const size_t base = (size_t)(rowBase + r) * (D / 4);
        #pragma unroll
        for (int j = 0; j < VEC; ++j)
            O4[base + t + j * TPB] = x[r][j];
    }
}

extern "C" void kernel_launch(void* const* d_in, const int* in_sizes, int n_in,
                              void* d_out, int out_size, void* d_ws, size_t ws_size,
                              hipStream_t stream) {
    const float* X  = (const float*)d_in[0];
    const float* ws = (const float*)d_in[1];
    const float* us = (const float*)d_in[2];
    const float* bs = (const float*)d_in[3];
    float* out   = (float*)d_out;
    float* coefs = (float*)d_ws;   // 40 floats of scratch

    coef_kernel<<<NF, 256, 0, stream>>>(ws, us, coefs);
    flow_kernel<<<S / ROWS, TPB, 0, stream>>>(X, ws, us, bs, coefs, out);
}

// Round 2
// 260.952 us; speedup vs baseline: 3.9745x; 3.9745x over previous
//
#include <hip/hip_runtime.h>
#include <math.h>

#define D      16384
#define D4     4096    // D/4 (float4 per row)
#define S      2048
#define NF     40
#define ROWS   8       // rows of X per block
#define TPB    1024
#define CH4    256     // float4 per chunk
#define CHUNK  1024    // floats per chunk
#define NCHUNK 16

// d_ws layout (float offsets)
#define WW_OFF   0       // WWt[k][j] = w_j . w_k      (1600)
#define UW_OFF   1600    // UWt[k][j] = u_j . w_k      (1600)
#define COEF_OFF 3200    // coef[j]                    (40)
#define GT_OFF   3240    // Gt[k][j] = uhat_j . w_k    (1600)
#define UH_OFF   8192    // uhat[k][d]                 (NF*D)
#define WS_FULL  (UH_OFF + NF * D)

__device__ __forceinline__ float dot4(float4 a, float4 b) {
    return fmaf(a.x, b.x, fmaf(a.y, b.y, fmaf(a.z, b.z, a.w * b.w)));
}

// ---------------------------------------------------------------------------
// k1: pairwise dots. Block k computes WWt[k][j] = w_j.w_k, UWt[k][j] = u_j.w_k
// ---------------------------------------------------------------------------
__global__ __launch_bounds__(TPB, 4) void pair_kernel(const float* __restrict__ Wg,
                                                      const float* __restrict__ Ug,
                                                      float* __restrict__ tbl) {
    const int k = blockIdx.x, t = threadIdx.x;
    const int wave = t >> 6, lane = t & 63;
    const float4* W4 = (const float4*)Wg;
    const float4* U4 = (const float4*)Ug;

    float aw[NF], au[NF];
    #pragma unroll
    for (int j = 0; j < NF; ++j) { aw[j] = 0.f; au[j] = 0.f; }

    for (int i = 0; i < 4; ++i) {
        float4 wk = W4[(size_t)k * D4 + i * TPB + t];
        #pragma unroll
        for (int j = 0; j < NF; ++j) {
            float4 wj = W4[(size_t)j * D4 + i * TPB + t];
            float4 uj = U4[(size_t)j * D4 + i * TPB + t];
            aw[j] += dot4(wk, wj);
            au[j] += dot4(wk, uj);
        }
    }
    #pragma unroll
    for (int j = 0; j < NF; ++j) {
        #pragma unroll
        for (int off = 32; off >= 1; off >>= 1) {
            aw[j] += __shfl_xor(aw[j], off);
            au[j] += __shfl_xor(au[j], off);
        }
    }
    __shared__ float red[16][2 * NF];
    if (lane == 0) {
        #pragma unroll
        for (int j = 0; j < NF; ++j) { red[wave][j] = aw[j]; red[wave][NF + j] = au[j]; }
    }
    __syncthreads();
    if (t < 2 * NF) {
        float s = 0.f;
        #pragma unroll
        for (int w = 0; w < 16; ++w) s += red[w][t];
        if (t < NF) tbl[WW_OFF + k * NF + t] = s;
        else        tbl[UW_OFF + k * NF + (t - NF)] = s;
    }
}

// ---------------------------------------------------------------------------
// k2: coefs + Gt (one 64-thread block)
// ---------------------------------------------------------------------------
__global__ void coef_g_kernel(float* __restrict__ tbl) {
    const int j = threadIdx.x;
    __shared__ float cS[64];
    if (j < NF) {
        float wwjj = tbl[WW_OFF + j * NF + j];
        float wujj = tbl[UW_OFF + j * NF + j];
        float sp = (wujj > 0.f) ? (wujj + log1pf(expf(-wujj))) : log1pf(expf(wujj));
        float coef = ((-1.f + sp) - wujj) / wwjj;
        tbl[COEF_OFF + j] = coef;
        cS[j] = coef;
    }
    __syncthreads();
    for (int e = j; e < NF * NF; e += 64) {
        int jj = e % NF;
        tbl[GT_OFF + e] = tbl[UW_OFF + e] + cS[jj] * tbl[WW_OFF + e];
    }
}

// ---------------------------------------------------------------------------
// k3: uhat[k] = u_k + coef_k * w_k  (only when ws is big enough)
// ---------------------------------------------------------------------------
__global__ __launch_bounds__(TPB, 4) void uhat_kernel(const float* __restrict__ Wg,
                                                      const float* __restrict__ Ug,
                                                      float* __restrict__ tbl) {
    const int k = blockIdx.x;
    const float cf = tbl[COEF_OFF + k];
    const float4* W4 = (const float4*)Wg;
    const float4* U4 = (const float4*)Ug;
    float4* UH4 = (float4*)(tbl + UH_OFF);
    for (int i = threadIdx.x; i < D4; i += TPB) {
        float4 w = W4[(size_t)k * D4 + i];
        float4 u = U4[(size_t)k * D4 + i];
        float4 r;
        r.x = fmaf(cf, w.x, u.x); r.y = fmaf(cf, w.y, u.y);
        r.z = fmaf(cf, w.z, u.z); r.w = fmaf(cf, w.w, u.w);
        UH4[(size_t)k * D4 + i] = r;
    }
}

// ---------------------------------------------------------------------------
// Main fused kernel: per block of 8 rows:
//   A: c0[r][k] = x0[r].w_k   (LDS-staged x chunks, 8 k-teams x 2 col-teams)
//   B: 40-step recurrence -> a[r][k]   (one wave per row)
//   C: out[r] = x0[r] + sum_k a[r][k]*uhat_k
// ---------------------------------------------------------------------------
template <bool PRE>
__global__ __launch_bounds__(TPB, 4) void flow_main(const float* __restrict__ Xg,
                                                    const float* __restrict__ Wg,
                                                    const float* __restrict__ Ug,
                                                    const float* __restrict__ Bg,
                                                    const float* __restrict__ tbl,
                                                    float* __restrict__ Og) {
    const int t = threadIdx.x;
    const int wave = t >> 6, lane = t & 63;
    const int rowBase = blockIdx.x * ROWS;

    __shared__ __align__(16) float xs[2][ROWS][CHUNK];   // 64 KB
    __shared__ __align__(16) float gts[NF][NF + 1];
    __shared__ __align__(16) float c0p[2][NF][ROWS];
    __shared__ __align__(16) float aTs[NF][ROWS];
    __shared__ float bsS[NF];
    __shared__ float coefS[NF];

    const float4* X4 = (const float4*)Xg;
    const float4* W4 = (const float4*)Wg;
    const float4* U4 = (const float4*)Ug;
    const float4* UH4 = (const float4*)(tbl + UH_OFF);

    // prologue: tables into LDS
    for (int e = t; e < NF * NF; e += TPB) gts[e / NF][e % NF] = tbl[GT_OFF + e];
    if (t < NF) { bsS[t] = Bg[t]; coefS[t] = tbl[COEF_OFF + t]; }

    // staging role: 2 rows x one float4 per thread per chunk
    const int srow = (t >> 8) * 2;
    const int sc4  = t & 255;

    float4 p0 = X4[(size_t)(rowBase + srow)     * D4 + sc4];
    float4 p1 = X4[(size_t)(rowBase + srow + 1) * D4 + sc4];
    *(float4*)&xs[0][srow][sc4 * 4]     = p0;
    *(float4*)&xs[0][srow + 1][sc4 * 4] = p1;
    __syncthreads();

    // ---- Phase A ----
    const int kt = wave >> 1, ct = wave & 1;
    const int k0 = kt * 5;

    float acc[ROWS][5];
    #pragma unroll
    for (int r = 0; r < ROWS; ++r)
        #pragma unroll
        for (int kk = 0; kk < 5; ++kk) acc[r][kk] = 0.f;

    int b = 0;
    for (int c = 0; c < NCHUNK; ++c) {
        if (c + 1 < NCHUNK) {
            p0 = X4[(size_t)(rowBase + srow)     * D4 + (c + 1) * CH4 + sc4];
            p1 = X4[(size_t)(rowBase + srow + 1) * D4 + (c + 1) * CH4 + sc4];
        }
        #pragma unroll
        for (int c4 = 0; c4 < 2; ++c4) {
            const int col4 = c * CH4 + ct * 128 + c4 * 64 + lane;
            float4 wv[5];
            #pragma unroll
            for (int kk = 0; kk < 5; ++kk)
                wv[kk] = W4[(size_t)(k0 + kk) * D4 + col4];
            const int lc = ct * 512 + c4 * 256 + lane * 4;
            #pragma unroll
            for (int r = 0; r < ROWS; ++r) {
                float4 xv = *(const float4*)&xs[b][r][lc];
                #pragma unroll
                for (int kk = 0; kk < 5; ++kk)
                    acc[r][kk] = fmaf(xv.x, wv[kk].x,
                                 fmaf(xv.y, wv[kk].y,
                                 fmaf(xv.z, wv[kk].z,
                                 fmaf(xv.w, wv[kk].w, acc[r][kk]))));
            }
        }
        if (c + 1 < NCHUNK) {
            *(float4*)&xs[b ^ 1][srow][sc4 * 4]     = p0;
            *(float4*)&xs[b ^ 1][srow + 1][sc4 * 4] = p1;
        }
        __syncthreads();
        b ^= 1;
    }

    // reduce partial dots across the wave, write c0 partials
    #pragma unroll
    for (int r = 0; r < ROWS; ++r)
        #pragma unroll
        for (int kk = 0; kk < 5; ++kk) {
            float v = acc[r][kk];
            #pragma unroll
            for (int off = 32; off >= 1; off >>= 1) v += __shfl_xor(v, off);
            acc[r][kk] = v;
        }
    if (lane == 0) {
        #pragma unroll
        for (int kk = 0; kk < 5; ++kk)
            #pragma unroll
            for (int r = 0; r < ROWS; ++r)
                c0p[ct][k0 + kk][r] = acc[r][kk];
    }
    __syncthreads();

    // ---- Phase B: recurrence, one wave per row ----
    if (wave < ROWS) {
        const int r = wave, j = lane;
        float aj = 0.f;
        for (int k = 0; k < NF; ++k) {
            float gv = (j < k) ? gts[k][j] : 0.f;
            float tv = aj * gv;
            #pragma unroll
            for (int off = 32; off >= 1; off >>= 1) tv += __shfl_xor(tv, off);
            float sum = c0p[0][k][r] + c0p[1][k][r] + bsS[k] + tv;
            float ak = tanhf(sum);
            if (j == k) aj = ak;
        }
        if (j < NF) aTs[j][r] = aj;
    }
    __syncthreads();

    // ---- Phase C: out = x0 + sum_k a[r][k] * uhat_k ----
    float4* O4 = (float4*)Og;
    #pragma unroll
    for (int p = 0; p < 2; ++p) {
        const int cb4 = p * 2048 + wave * 128;
        float4 o[ROWS][2];
        #pragma unroll
        for (int r = 0; r < ROWS; ++r)
            #pragma unroll
            for (int cc = 0; cc < 2; ++cc)
                o[r][cc] = X4[(size_t)(rowBase + r) * D4 + cb4 + cc * 64 + lane];

        for (int k = 0; k < NF; ++k) {
            float4 alo = *(const float4*)&aTs[k][0];
            float4 ahi = *(const float4*)&aTs[k][4];
            float4 uh[2];
            #pragma unroll
            for (int cc = 0; cc < 2; ++cc) {
                const size_t gi = (size_t)k * D4 + cb4 + cc * 64 + lane;
                if (PRE) {
                    uh[cc] = UH4[gi];
                } else {
                    float4 uu = U4[gi], wv = W4[gi];
                    float cf = coefS[k];
                    uh[cc].x = fmaf(cf, wv.x, uu.x);
                    uh[cc].y = fmaf(cf, wv.y, uu.y);
                    uh[cc].z = fmaf(cf, wv.z, uu.z);
                    uh[cc].w = fmaf(cf, wv.w, uu.w);
                }
            }
            #pragma unroll
            for (int cc = 0; cc < 2; ++cc) {
                o[0][cc].x = fmaf(alo.x, uh[cc].x, o[0][cc].x);
                o[0][cc].y = fmaf(alo.x, uh[cc].y, o[0][cc].y);
                o[0][cc].z = fmaf(alo.x, uh[cc].z, o[0][cc].z);
                o[0][cc].w = fmaf(alo.x, uh[cc].w, o[0][cc].w);
                o[1][cc].x = fmaf(alo.y, uh[cc].x, o[1][cc].x);
                o[1][cc].y = fmaf(alo.y, uh[cc].y, o[1][cc].y);
                o[1][cc].z = fmaf(alo.y, uh[cc].z, o[1][cc].z);
                o[1][cc].w = fmaf(alo.y, uh[cc].w, o[1][cc].w);
                o[2][cc].x = fmaf(alo.z, uh[cc].x, o[2][cc].x);
                o[2][cc].y = fmaf(alo.z, uh[cc].y, o[2][cc].y);
                o[2][cc].z = fmaf(alo.z, uh[cc].z, o[2][cc].z);
                o[2][cc].w = fmaf(alo.z, uh[cc].w, o[2][cc].w);
                o[3][cc].x = fmaf(alo.w, uh[cc].x, o[3][cc].x);
                o[3][cc].y = fmaf(alo.w, uh[cc].y, o[3][cc].y);
                o[3][cc].z = fmaf(alo.w, uh[cc].z, o[3][cc].z);
                o[3][cc].w = fmaf(alo.w, uh[cc].w, o[3][cc].w);
                o[4][cc].x = fmaf(ahi.x, uh[cc].x, o[4][cc].x);
                o[4][cc].y = fmaf(ahi.x, uh[cc].y, o[4][cc].y);
                o[4][cc].z = fmaf(ahi.x, uh[cc].z, o[4][cc].z);
                o[4][cc].w = fmaf(ahi.x, uh[cc].w, o[4][cc].w);
                o[5][cc].x = fmaf(ahi.y, uh[cc].x, o[5][cc].x);
                o[5][cc].y = fmaf(ahi.y, uh[cc].y, o[5][cc].y);
                o[5][cc].z = fmaf(ahi.y, uh[cc].z, o[5][cc].z);
                o[5][cc].w = fmaf(ahi.y, uh[cc].w, o[5][cc].w);
                o[6][cc].x = fmaf(ahi.z, uh[cc].x, o[6][cc].x);
                o[6][cc].y = fmaf(ahi.z, uh[cc].y, o[6][cc].y);
                o[6][cc].z = fmaf(ahi.z, uh[cc].z, o[6][cc].z);
                o[6][cc].w = fmaf(ahi.z, uh[cc].w, o[6][cc].w);
                o[7][cc].x = fmaf(ahi.w, uh[cc].x, o[7][cc].x);
                o[7][cc].y = fmaf(ahi.w, uh[cc].y, o[7][cc].y);
                o[7][cc].z = fmaf(ahi.w, uh[cc].z, o[7][cc].z);
                o[7][cc].w = fmaf(ahi.w, uh[cc].w, o[7][cc].w);
            }
        }
        #pragma unroll
        for (int r = 0; r < ROWS; ++r)
            #pragma unroll
            for (int cc = 0; cc < 2; ++cc)
                O4[(size_t)(rowBase + r) * D4 + cb4 + cc * 64 + lane] = o[r][cc];
    }
}

extern "C" void kernel_launch(void* const* d_in, const int* in_sizes, int n_in,
                              void* d_out, int out_size, void* d_ws, size_t ws_size,
                              hipStream_t stream) {
    const float* X  = (const float*)d_in[0];
    const float* Wg = (const float*)d_in[1];
    const float* Ug = (const float*)d_in[2];
    const float* Bg = (const float*)d_in[3];
    float* out = (float*)d_out;
    float* tbl = (float*)d_ws;

    const bool pre = ws_size >= (size_t)WS_FULL * sizeof(float);

    pair_kernel<<<NF, TPB, 0, stream>>>(Wg, Ug, tbl);
    coef_g_kernel<<<1, 64, 0, stream>>>(tbl);
    if (pre) {
        uhat_kernel<<<NF, TPB, 0, stream>>>(Wg, Ug, tbl);
        flow_main<true><<<S / ROWS, TPB, 0, stream>>>(X, Wg, Ug, Bg, tbl, out);
    } else {
        flow_main<false><<<S / ROWS, TPB, 0, stream>>>(X, Wg, Ug, Bg, tbl, out);
    }
}

// Round 3
// 161.568 us; speedup vs baseline: 6.4192x; 1.6151x over previous
//
#include <hip/hip_runtime.h>
#include <math.h>

#define D      16384
#define D4     4096    // D/4 (float4 per row)
#define S      2048
#define NF     40
#define ROWS   8       // rows of X per block
#define TPB    1024
#define CH4    256     // float4 per chunk
#define CHUNK  1024    // floats per chunk
#define NCHUNK 16

// d_ws layout (float offsets)
#define WW_OFF   0       // WWt[k][j] = w_j . w_k      (1600)
#define UW_OFF   1600    // UWt[k][j] = u_j . w_k      (1600)
#define COEF_OFF 3200    // coef[j]                    (40)
#define GT_OFF   3240    // Gt[k][j] = uhat_j . w_k    (1600)
#define UH_OFF   8192    // uhat[k][d]                 (NF*D)
#define WS_FULL  (UH_OFF + NF * D)
#define WS_MIN   (GT_OFF + NF * NF)

__device__ __forceinline__ float dot4(float4 a, float4 b) {
    return fmaf(a.x, b.x, fmaf(a.y, b.y, fmaf(a.z, b.z, a.w * b.w)));
}

// ---------------------------------------------------------------------------
// k1: block (k, h): dots WW[k][j], UW[k][j] for j in [5h, 5h+5), own coef_k,
//     and (if doUhat) uhat[k] slice [512h*4 .. ) of f4 columns.
//     grid = 40*8 = 320 blocks, TPB 512.
// ---------------------------------------------------------------------------
__global__ __launch_bounds__(512) void pair_uhat_kernel(const float* __restrict__ Wg,
                                                        const float* __restrict__ Ug,
                                                        float* __restrict__ tbl,
                                                        int doUhat) {
    const int k = blockIdx.x >> 3;
    const int h = blockIdx.x & 7;
    const int j0 = h * 5;
    const int t = threadIdx.x;
    const int wave = t >> 6, lane = t & 63;

    const float4* W4 = (const float4*)Wg;
    const float4* U4 = (const float4*)Ug;

    float ww[5], wu[5], wkk = 0.f, wku = 0.f;
    #pragma unroll
    for (int j = 0; j < 5; ++j) { ww[j] = 0.f; wu[j] = 0.f; }

    for (int i = 0; i < 8; ++i) {
        const int pos = i * 512 + t;
        float4 wk = W4[(size_t)k * D4 + pos];
        float4 uk = U4[(size_t)k * D4 + pos];
        wkk += dot4(wk, wk);
        wku += dot4(wk, uk);
        #pragma unroll
        for (int j = 0; j < 5; ++j) {
            float4 wj = W4[(size_t)(j0 + j) * D4 + pos];
            float4 uj = U4[(size_t)(j0 + j) * D4 + pos];
            ww[j] += dot4(wk, wj);
            wu[j] += dot4(wk, uj);
        }
    }

    float v[12];
    #pragma unroll
    for (int j = 0; j < 5; ++j) { v[j] = ww[j]; v[5 + j] = wu[j]; }
    v[10] = wkk; v[11] = wku;
    #pragma unroll
    for (int e = 0; e < 12; ++e) {
        #pragma unroll
        for (int off = 32; off >= 1; off >>= 1) v[e] += __shfl_xor(v[e], off);
    }

    __shared__ float red[8][12];
    __shared__ float fin[12];
    __shared__ float coefL;
    if (lane == 0) {
        #pragma unroll
        for (int e = 0; e < 12; ++e) red[wave][e] = v[e];
    }
    __syncthreads();
    if (t < 12) {
        float s = 0.f;
        #pragma unroll
        for (int w = 0; w < 8; ++w) s += red[w][t];
        fin[t] = s;
        if (t < 5)       tbl[WW_OFF + k * NF + j0 + t] = s;
        else if (t < 10) tbl[UW_OFF + k * NF + j0 + (t - 5)] = s;
    }
    __syncthreads();
    if (t == 0) {
        float wwd = fin[10], wud = fin[11];
        float sp = (wud > 0.f) ? (wud + log1pf(expf(-wud))) : log1pf(expf(wud));
        float cf = ((-1.f + sp) - wud) / wwd;
        coefL = cf;
        if (h == 0) tbl[COEF_OFF + k] = cf;
    }
    __syncthreads();

    if (doUhat) {
        const float cf = coefL;
        float4* UH4 = (float4*)(tbl + UH_OFF);
        const int pos = h * 512 + t;   // one f4 per thread, 512*8 = 4096 = D4
        float4 w = W4[(size_t)k * D4 + pos];
        float4 u = U4[(size_t)k * D4 + pos];
        float4 r;
        r.x = fmaf(cf, w.x, u.x); r.y = fmaf(cf, w.y, u.y);
        r.z = fmaf(cf, w.z, u.z); r.w = fmaf(cf, w.w, u.w);
        UH4[(size_t)k * D4 + pos] = r;
    }
}

// ---------------------------------------------------------------------------
// k2: Gt[k][j] = UW[k][j] + coef_j * WW[k][j]   (one small block)
// ---------------------------------------------------------------------------
__global__ void g_kernel(float* __restrict__ tbl) {
    __shared__ float cS[NF];
    const int t = threadIdx.x;
    if (t < NF) cS[t] = tbl[COEF_OFF + t];
    __syncthreads();
    for (int e = t; e < NF * NF; e += 256) {
        int j = e % NF;
        tbl[GT_OFF + e] = tbl[UW_OFF + e] + cS[j] * tbl[WW_OFF + e];
    }
}

// ---------------------------------------------------------------------------
// Main fused kernel (grid 256, TPB 1024, 8 rows/block):
//   A: c0[r][k] = x0[r].w_k   (LDS-staged x chunks, 8 k-teams x 2 col-teams)
//   B: 40-step recurrence -> a[r][k]   (one wave per row)
//   C: out[r] = x0[r] + sum_k a[r][k]*uhat_k
// NOTE: no min-occupancy arg on launch_bounds — round-2's (1024,4) capped
// VGPRs at 64 and spilled Phase C's 64-float accumulator to scratch.
// ---------------------------------------------------------------------------
template <bool PRE>
__global__ __launch_bounds__(TPB) void flow_main(const float* __restrict__ Xg,
                                                 const float* __restrict__ Wg,
                                                 const float* __restrict__ Ug,
                                                 const float* __restrict__ Bg,
                                                 const float* __restrict__ tbl,
                                                 float* __restrict__ Og) {
    const int t = threadIdx.x;
    const int wave = t >> 6, lane = t & 63;
    const int rowBase = blockIdx.x * ROWS;

    __shared__ __align__(16) float xs[2][ROWS][CHUNK];   // 64 KB
    __shared__ __align__(16) float gts[NF][NF + 1];
    __shared__ __align__(16) float c0p[2][NF][ROWS];
    __shared__ __align__(16) float aTs[NF][ROWS];
    __shared__ float bsS[NF];
    __shared__ float coefS[NF];

    const float4* X4 = (const float4*)Xg;
    const float4* W4 = (const float4*)Wg;
    const float4* U4 = (const float4*)Ug;
    const float4* UH4 = (const float4*)(tbl + UH_OFF);

    // prologue: tables into LDS
    for (int e = t; e < NF * NF; e += TPB) gts[e / NF][e % NF] = tbl[GT_OFF + e];
    if (t < NF) { bsS[t] = Bg[t]; coefS[t] = tbl[COEF_OFF + t]; }

    // staging role: 2 rows x one float4 per thread per chunk
    const int srow = (t >> 8) * 2;
    const int sc4  = t & 255;

    float4 p0 = X4[(size_t)(rowBase + srow)     * D4 + sc4];
    float4 p1 = X4[(size_t)(rowBase + srow + 1) * D4 + sc4];
    *(float4*)&xs[0][srow][sc4 * 4]     = p0;
    *(float4*)&xs[0][srow + 1][sc4 * 4] = p1;
    __syncthreads();

    // ---- Phase A ----
    const int kt = wave >> 1, ct = wave & 1;
    const int k0 = kt * 5;

    float acc[ROWS][5];
    #pragma unroll
    for (int r = 0; r < ROWS; ++r)
        #pragma unroll
        for (int kk = 0; kk < 5; ++kk) acc[r][kk] = 0.f;

    int b = 0;
    for (int c = 0; c < NCHUNK; ++c) {
        if (c + 1 < NCHUNK) {
            p0 = X4[(size_t)(rowBase + srow)     * D4 + (c + 1) * CH4 + sc4];
            p1 = X4[(size_t)(rowBase + srow + 1) * D4 + (c + 1) * CH4 + sc4];
        }
        #pragma unroll
        for (int c4 = 0; c4 < 2; ++c4) {
            const int col4 = c * CH4 + ct * 128 + c4 * 64 + lane;
            float4 wv[5];
            #pragma unroll
            for (int kk = 0; kk < 5; ++kk)
                wv[kk] = W4[(size_t)(k0 + kk) * D4 + col4];
            const int lc = ct * 512 + c4 * 256 + lane * 4;
            #pragma unroll
            for (int r = 0; r < ROWS; ++r) {
                float4 xv = *(const float4*)&xs[b][r][lc];
                #pragma unroll
                for (int kk = 0; kk < 5; ++kk)
                    acc[r][kk] = fmaf(xv.x, wv[kk].x,
                                 fmaf(xv.y, wv[kk].y,
                                 fmaf(xv.z, wv[kk].z,
                                 fmaf(xv.w, wv[kk].w, acc[r][kk]))));
            }
        }
        if (c + 1 < NCHUNK) {
            *(float4*)&xs[b ^ 1][srow][sc4 * 4]     = p0;
            *(float4*)&xs[b ^ 1][srow + 1][sc4 * 4] = p1;
        }
        __syncthreads();
        b ^= 1;
    }

    // reduce partial dots across the wave, write c0 partials
    #pragma unroll
    for (int r = 0; r < ROWS; ++r)
        #pragma unroll
        for (int kk = 0; kk < 5; ++kk) {
            float v = acc[r][kk];
            #pragma unroll
            for (int off = 32; off >= 1; off >>= 1) v += __shfl_xor(v, off);
            acc[r][kk] = v;
        }
    if (lane == 0) {
        #pragma unroll
        for (int kk = 0; kk < 5; ++kk)
            #pragma unroll
            for (int r = 0; r < ROWS; ++r)
                c0p[ct][k0 + kk][r] = acc[r][kk];
    }
    __syncthreads();

    // ---- issue Phase C p=0 X re-loads now (overlap with Phase B) ----
    float4 o[ROWS][2];
    {
        const int cb4 = wave * 128;
        #pragma unroll
        for (int r = 0; r < ROWS; ++r)
            #pragma unroll
            for (int cc = 0; cc < 2; ++cc)
                o[r][cc] = X4[(size_t)(rowBase + r) * D4 + cb4 + cc * 64 + lane];
    }

    // ---- Phase B: recurrence, one wave per row ----
    if (wave < ROWS) {
        const int r = wave, j = lane;
        float aj = 0.f;
        for (int k = 0; k < NF; ++k) {
            float gv = (j < k) ? gts[k][j] : 0.f;
            float tv = aj * gv;
            #pragma unroll
            for (int off = 32; off >= 1; off >>= 1) tv += __shfl_xor(tv, off);
            float sum = c0p[0][k][r] + c0p[1][k][r] + bsS[k] + tv;
            float ak = tanhf(sum);
            if (j == k) aj = ak;
        }
        if (j < NF) aTs[j][r] = aj;
    }
    __syncthreads();

    // ---- Phase C: out = x0 + sum_k a[r][k] * uhat_k ----
    float4* O4 = (float4*)Og;
    #pragma unroll
    for (int p = 0; p < 2; ++p) {
        const int cb4 = p * 2048 + wave * 128;
        if (p == 1) {
            #pragma unroll
            for (int r = 0; r < ROWS; ++r)
                #pragma unroll
                for (int cc = 0; cc < 2; ++cc)
                    o[r][cc] = X4[(size_t)(rowBase + r) * D4 + cb4 + cc * 64 + lane];
        }

        for (int k = 0; k < NF; ++k) {
            float4 alo = *(const float4*)&aTs[k][0];
            float4 ahi = *(const float4*)&aTs[k][4];
            float4 uh[2];
            #pragma unroll
            for (int cc = 0; cc < 2; ++cc) {
                const size_t gi = (size_t)k * D4 + cb4 + cc * 64 + lane;
                if (PRE) {
                    uh[cc] = UH4[gi];
                } else {
                    float4 uu = U4[gi], wv = W4[gi];
                    float cf = coefS[k];
                    uh[cc].x = fmaf(cf, wv.x, uu.x);
                    uh[cc].y = fmaf(cf, wv.y, uu.y);
                    uh[cc].z = fmaf(cf, wv.z, uu.z);
                    uh[cc].w = fmaf(cf, wv.w, uu.w);
                }
            }
            #pragma unroll
            for (int cc = 0; cc < 2; ++cc) {
                o[0][cc].x = fmaf(alo.x, uh[cc].x, o[0][cc].x);
                o[0][cc].y = fmaf(alo.x, uh[cc].y, o[0][cc].y);
                o[0][cc].z = fmaf(alo.x, uh[cc].z, o[0][cc].z);
                o[0][cc].w = fmaf(alo.x, uh[cc].w, o[0][cc].w);
                o[1][cc].x = fmaf(alo.y, uh[cc].x, o[1][cc].x);
                o[1][cc].y = fmaf(alo.y, uh[cc].y, o[1][cc].y);
                o[1][cc].z = fmaf(alo.y, uh[cc].z, o[1][cc].z);
                o[1][cc].w = fmaf(alo.y, uh[cc].w, o[1][cc].w);
                o[2][cc].x = fmaf(alo.z, uh[cc].x, o[2][cc].x);
                o[2][cc].y = fmaf(alo.z, uh[cc].y, o[2][cc].y);
                o[2][cc].z = fmaf(alo.z, uh[cc].z, o[2][cc].z);
                o[2][cc].w = fmaf(alo.z, uh[cc].w, o[2][cc].w);
                o[3][cc].x = fmaf(alo.w, uh[cc].x, o[3][cc].x);
                o[3][cc].y = fmaf(alo.w, uh[cc].y, o[3][cc].y);
                o[3][cc].z = fmaf(alo.w, uh[cc].z, o[3][cc].z);
                o[3][cc].w = fmaf(alo.w, uh[cc].w, o[3][cc].w);
                o[4][cc].x = fmaf(ahi.x, uh[cc].x, o[4][cc].x);
                o[4][cc].y = fmaf(ahi.x, uh[cc].y, o[4][cc].y);
                o[4][cc].z = fmaf(ahi.x, uh[cc].z, o[4][cc].z);
                o[4][cc].w = fmaf(ahi.x, uh[cc].w, o[4][cc].w);
                o[5][cc].x = fmaf(ahi.y, uh[cc].x, o[5][cc].x);
                o[5][cc].y = fmaf(ahi.y, uh[cc].y, o[5][cc].y);
                o[5][cc].z = fmaf(ahi.y, uh[cc].z, o[5][cc].z);
                o[5][cc].w = fmaf(ahi.y, uh[cc].w, o[5][cc].w);
                o[6][cc].x = fmaf(ahi.z, uh[cc].x, o[6][cc].x);
                o[6][cc].y = fmaf(ahi.z, uh[cc].y, o[6][cc].y);
                o[6][cc].z = fmaf(ahi.z, uh[cc].z, o[6][cc].z);
                o[6][cc].w = fmaf(ahi.z, uh[cc].w, o[6][cc].w);
                o[7][cc].x = fmaf(ahi.w, uh[cc].x, o[7][cc].x);
                o[7][cc].y = fmaf(ahi.w, uh[cc].y, o[7][cc].y);
                o[7][cc].z = fmaf(ahi.w, uh[cc].z, o[7][cc].z);
                o[7][cc].w = fmaf(ahi.w, uh[cc].w, o[7][cc].w);
            }
        }
        #pragma unroll
        for (int r = 0; r < ROWS; ++r)
            #pragma unroll
            for (int cc = 0; cc < 2; ++cc)
                O4[(size_t)(rowBase + r) * D4 + cb4 + cc * 64 + lane] = o[r][cc];
    }
}

extern "C" void kernel_launch(void* const* d_in, const int* in_sizes, int n_in,
                              void* d_out, int out_size, void* d_ws, size_t ws_size,
                              hipStream_t stream) {
    const float* X  = (const float*)d_in[0];
    const float* Wg = (const float*)d_in[1];
    const float* Ug = (const float*)d_in[2];
    const float* Bg = (const float*)d_in[3];
    float* out = (float*)d_out;
    float* tbl = (float*)d_ws;

    const bool pre = ws_size >= (size_t)WS_FULL * sizeof(float);

    pair_uhat_kernel<<<NF * 8, 512, 0, stream>>>(Wg, Ug, tbl, pre ? 1 : 0);
    g_kernel<<<1, 256, 0, stream>>>(tbl);
    if (pre) {
        flow_main<true><<<S / ROWS, TPB, 0, stream>>>(X, Wg, Ug, Bg, tbl, out);
    } else {
        flow_main<false><<<S / ROWS, TPB, 0, stream>>>(X, Wg, Ug, Bg, tbl, out);
    }
}